// Round 13
// baseline (410.636 us; speedup 1.0000x reference)
//
#include <hip/hip_runtime.h>
#include <hip/hip_bf16.h>
#include <stdint.h>

// Problem constants
#define B_ 4
#define T_ 2048
#define E_ 1024
#define H_ 16
#define D_ 64
#define M_ (B_ * T_)  // 8192 rows

typedef unsigned short u16;
typedef unsigned int u32;
typedef short s16x8 __attribute__((ext_vector_type(8)));
typedef unsigned short u16x8 __attribute__((ext_vector_type(8)));
typedef float f32x4 __attribute__((ext_vector_type(4)));
typedef unsigned int u32x2 __attribute__((ext_vector_type(2)));

// LDS pitch 72 u16 = 144 B (16B-aligned rows, ~2-way bank conflicts, free).
// HARD RULE (r6/r8/r11 forensics): total static LDS per kernel must be
// <= 65536 B — beyond hipDeviceProp.sharedMemPerBlock is UB (NaN/crash).
#define LP_ 72

__device__ __forceinline__ u16 f2bf(float f) {
    __hip_bfloat16 h = __float2bfloat16(f);
    return __builtin_bit_cast(u16, h);
}
__device__ __forceinline__ float bf2f(u16 u) {
    unsigned int v = ((unsigned int)u) << 16;
    return __builtin_bit_cast(float, v);
}
__device__ __forceinline__ u32 pk2(float a, float b) {
    return (u32)f2bf(a) | ((u32)f2bf(b) << 16);
}

// async global->LDS 16B copy (dest wave-uniform base + lane*16 — m104).
typedef __attribute__((address_space(1))) const void as1_void;
typedef __attribute__((address_space(3))) void as3_void;
__device__ __forceinline__ void gload16(const void* g, void* l) {
    __builtin_amdgcn_global_load_lds(
        reinterpret_cast<as1_void*>(reinterpret_cast<uintptr_t>(g)),
        reinterpret_cast<as3_void*>(reinterpret_cast<uintptr_t>(l)),
        16, 0, 0);
}

// ---------------------------------------------------------------------------
// Dtype probe (block-cooperative, 256 threads).
// ---------------------------------------------------------------------------
__device__ __forceinline__ int block_probe_is_bf16(const void* x, int tid) {
    const u16* p = (const u16*)x;
    u16 u = p[tid];
    int e = (u >> 7) & 0xFF;
    int ok = ((u & 0x7FFF) == 0 || (e >= 103 && e <= 133)) ? 1 : 0;
    return (__syncthreads_count(ok) >= 240) ? 1 : 0;
}

// ---------------------------------------------------------------------------
// GEMM building blocks, pitch-72 family (reg-staged; used by gemm_f32out and
// gemm_v_fused — r9-green, frozen).
// ---------------------------------------------------------------------------
__device__ __forceinline__ void load_a_regs(
    int a_bf, const u16* abase_bf, const float* abase_f, int kk, u16x8 (&av)[4])
{
    if (a_bf) {
        #pragma unroll
        for (int j = 0; j < 4; j++) av[j] = *(const u16x8*)(abase_bf + kk + j * 8);
    } else {
        #pragma unroll
        for (int j = 0; j < 4; j++) {
            f32x4 t0 = *(const f32x4*)(abase_f + kk + j * 8);
            f32x4 t1 = *(const f32x4*)(abase_f + kk + j * 8 + 4);
            u16x8 o;
            #pragma unroll
            for (int e = 0; e < 4; e++) { o[e] = f2bf(t0[e]); o[4 + e] = f2bf(t1[e]); }
            av[j] = o;
        }
    }
}
__device__ __forceinline__ void load_b_regs(const u16* bbase, int kk, u16x8 (&bv)[4]) {
    #pragma unroll
    for (int j = 0; j < 4; j++) bv[j] = *(const u16x8*)(bbase + kk + j * 8);
}
__device__ __forceinline__ void write_lds72(
    u16* l, int srow, int soff, const u16x8 (&v)[4])
{
    #pragma unroll
    for (int j = 0; j < 4; j++)
        *(u16x8*)&l[srow * LP_ + soff + j * 8] = v[j];
}
__device__ __forceinline__ void mfma_tile72(
    const u16* al, const u16* bl, f32x4 (&acc)[4][4],
    int wm, int wn, int lane15, int quad)
{
    #pragma unroll
    for (int ks = 0; ks < 2; ks++) {
        s16x8 af[4], bfr[4];
        #pragma unroll
        for (int i = 0; i < 4; i++)
            af[i] = *(const s16x8*)&al[(wm + i * 16 + lane15) * LP_ + ks * 32 + quad * 8];
        #pragma unroll
        for (int j = 0; j < 4; j++)
            bfr[j] = *(const s16x8*)&bl[(wn + j * 16 + lane15) * LP_ + ks * 32 + quad * 8];
        #pragma unroll
        for (int i = 0; i < 4; i++)
            #pragma unroll
            for (int j = 0; j < 4; j++)
                acc[i][j] = __builtin_amdgcn_mfma_f32_16x16x32_bf16(af[i], bfr[j], acc[i][j], 0, 0, 0);
    }
}

// ---------------------------------------------------------------------------
// Pitch-64 (linear) family for the gload_lds-staged gemm_qkv (r4-proven):
// staging geometry: wave w op j covers LDS rows [w*32+j*8, +8); lane covers
// row w*32+j*8+(lane>>3), u16 cols [(lane&7)*8, +8).
// ---------------------------------------------------------------------------
__device__ __forceinline__ void stage_bf64(const u16* g, int kk, u16* l, int wave) {
    #pragma unroll
    for (int j = 0; j < 4; j++)
        gload16(g + (size_t)j * 8 * E_ + kk, l + (wave * 4 + j) * 512);
}
__device__ __forceinline__ void stage_a_f32_64(
    const float* abase_f, int kk, u16* al, int srow, int soff)
{
    #pragma unroll
    for (int j = 0; j < 4; j++) {
        f32x4 t0 = *(const f32x4*)(abase_f + kk + j * 8);
        f32x4 t1 = *(const f32x4*)(abase_f + kk + j * 8 + 4);
        u16x8 o;
        #pragma unroll
        for (int e = 0; e < 4; e++) { o[e] = f2bf(t0[e]); o[4 + e] = f2bf(t1[e]); }
        *(u16x8*)&al[srow * 64 + soff + j * 8] = o;
    }
}
__device__ __forceinline__ void mfma_tile64(
    const u16* al, const u16* bl, f32x4 (&acc)[4][4],
    int wm, int wn, int lane15, int quad)
{
    #pragma unroll
    for (int ks = 0; ks < 2; ks++) {
        s16x8 af[4], bfr[4];
        #pragma unroll
        for (int i = 0; i < 4; i++)
            af[i] = *(const s16x8*)&al[(wm + i * 16 + lane15) * 64 + ks * 32 + quad * 8];
        #pragma unroll
        for (int j = 0; j < 4; j++)
            bfr[j] = *(const s16x8*)&bl[(wn + j * 16 + lane15) * 64 + ks * 32 + quad * 8];
        #pragma unroll
        for (int i = 0; i < 4; i++)
            #pragma unroll
            for (int j = 0; j < 4; j++)
                acc[i][j] = __builtin_amdgcn_mfma_f32_16x16x32_bf16(af[i], bfr[j], acc[i][j], 0, 0, 0);
    }
}

// ---------------------------------------------------------------------------
// bf16 transpose for FOUR weight matrices in one launch: W[k][n] -> Wt[n][k]
// ---------------------------------------------------------------------------
__global__ __launch_bounds__(256) void transpose_w4_kernel(
    const void* __restrict__ w0, const void* __restrict__ w1,
    const void* __restrict__ w2, const void* __restrict__ w3,
    u16* __restrict__ o0, u16* __restrict__ o1,
    u16* __restrict__ o2, u16* __restrict__ o3,
    const void* __restrict__ xprobe)
{
    __shared__ u16 th[64][66];
    const int x = threadIdx.x, y = threadIdx.y;
    const int isbf = block_probe_is_bf16(xprobe, y * 64 + x);
    const int z = (int)blockIdx.z;
    const void* in = (z == 0) ? w0 : (z == 1) ? w1 : (z == 2) ? w2 : w3;
    u16* o = (z == 0) ? o0 : (z == 1) ? o1 : (z == 2) ? o2 : o3;
    const int r0 = blockIdx.y * 64;
    const int c0 = blockIdx.x * 64;
    #pragma unroll
    for (int j = 0; j < 16; j++) {
        const size_t idx = (size_t)(r0 + y * 16 + j) * E_ + c0 + x;
        float v = isbf ? bf2f(((const u16*)in)[idx]) : ((const float*)in)[idx];
        th[y * 16 + j][x] = f2bf(v);
    }
    __syncthreads();
    #pragma unroll
    for (int j = 0; j < 16; j++)
        o[(size_t)(c0 + y * 16 + j) * E_ + r0 + x] = th[x][y * 16 + j];
}

// ---------------------------------------------------------------------------
// All four biases -> fp32 (bq|bk|bv|bo)
// ---------------------------------------------------------------------------
__global__ __launch_bounds__(256) void convert_bias_kernel(
    const void* __restrict__ bq, const void* __restrict__ bk,
    const void* __restrict__ bv, const void* __restrict__ bo,
    float* __restrict__ outb, const void* __restrict__ xprobe)
{
    const int isbf = block_probe_is_bf16(xprobe, threadIdx.x);
    const int i = blockIdx.x * 256 + threadIdx.x;  // < 1024
    const int w = blockIdx.y;
    const void* p = (w == 0) ? bq : (w == 1) ? bk : (w == 2) ? bv : bo;
    float v = isbf ? bf2f(((const u16*)p)[i]) : ((const float*)p)[i];
    outb[w * 1024 + i] = v;
}

// ---------------------------------------------------------------------------
// bf16 MFMA GEMM, fp32 out. r9-GREEN two-barrier reg-staged prefetch loop,
// UNCHANGED — drain-style control vs gemm_qkv's counted-vmcnt pipeline.
// ---------------------------------------------------------------------------
__global__ __launch_bounds__(256) void gemm_f32out_kernel(
    const void* __restrict__ A, int a_mode, int m_base,
    const u16* __restrict__ Bt, const float* __restrict__ bias,
    float* __restrict__ Cout, int ldc)
{
    __shared__ u16 a_lds[128 * LP_];
    __shared__ u16 b_lds[128 * LP_];
    const int tid = threadIdx.x;
    const int isbf = block_probe_is_bf16(A, tid);
    const int a_bf = (a_mode < 0) ? isbf : a_mode;
    const int wave = tid >> 6, lane = tid & 63;
    const int lane15 = lane & 15, quad = lane >> 4;
    const int wm = (wave & 1) * 64, wn = (wave >> 1) * 64;
    const int nwg = (int)(gridDim.x * gridDim.y);
    const int lin = (int)(blockIdx.y * gridDim.x + blockIdx.x);
    const int swz = (lin & 7) * (nwg >> 3) + (lin >> 3);
    const int m0 = (swz / (int)gridDim.x) * 128;
    const int n0 = (swz % (int)gridDim.x) * 128;
    const int srow = tid >> 1;
    const int soff = (tid & 1) * 32;

    f32x4 acc[4][4];
    #pragma unroll
    for (int i = 0; i < 4; i++)
        #pragma unroll
        for (int j = 0; j < 4; j++) acc[i][j] = (f32x4)0.0f;

    const u16* abase_bf = (const u16*)A + (size_t)(m_base + m0 + srow) * E_ + soff;
    const float* abase_f = (const float*)A + (size_t)(m_base + m0 + srow) * E_ + soff;
    const u16* bbase = Bt + (size_t)(n0 + srow) * E_ + soff;

    u16x8 av[4], bv[4];
    load_a_regs(a_bf, abase_bf, abase_f, 0, av);
    load_b_regs(bbase, 0, bv);

    for (int kk = 0; kk < E_; kk += 64) {
        __syncthreads();   // previous tile's MFMA reads done
        write_lds72(a_lds, srow, soff, av);
        write_lds72(b_lds, srow, soff, bv);
        __syncthreads();   // staging visible
        if (kk + 64 < E_) {  // prefetch next tile; in flight across MFMA
            load_a_regs(a_bf, abase_bf, abase_f, kk + 64, av);
            load_b_regs(bbase, kk + 64, bv);
        }
        mfma_tile72(a_lds, b_lds, acc, wm, wn, lane15, quad);
    }

    #pragma unroll
    for (int j = 0; j < 4; j++) {
        const int col = n0 + wn + j * 16 + lane15;
        const float bb = bias[col];
        #pragma unroll
        for (int i = 0; i < 4; i++) {
            const int row = m0 + wm + i * 16 + quad * 4;
            #pragma unroll
            for (int r = 0; r < 4; r++)
                Cout[(size_t)(row + r) * ldc + col] = acc[i][j][r] + bb;
        }
    }
}

// ---------------------------------------------------------------------------
// FUSED Q|K|V projection GEMM (Path A) — COUNTED-vmcnt 2-phase pipeline (T4):
// double-buffered gload_lds staging (r4-green structure + LDS size 65536 B,
// the proven-safe maximum). Per step: issue next tile's 8 global_load_lds;
// s_waitcnt vmcnt(8) (in-order retirement => waits exactly the PREVIOUS
// tile's 8); raw s_barrier (collective: each wave certified its own loads);
// 32 MFMA; raw s_barrier (NO drain — the 8 new loads stay in flight across
// it, which __syncthreads' implicit vmcnt(0) forbids — the m233 stall).
// fp32-probe fallback path uses plain __syncthreads (uniform branch).
// ---------------------------------------------------------------------------
__global__ __launch_bounds__(256) void gemm_qkv_kernel(
    const void* __restrict__ A, const u16* __restrict__ Bt,
    const float* __restrict__ bias, float* __restrict__ Cout,
    u16* __restrict__ Vt)
{
    __shared__ u16 smem[4 * 128 * 64];  // a0|a1|b0|b1 = 65536 B exactly
    const int tid = threadIdx.x;
    const int isbf = block_probe_is_bf16(A, tid);
    const int wave = tid >> 6, lane = tid & 63;
    const int lane15 = lane & 15, quad = lane >> 4;
    const int wm = (wave & 1) * 64, wn = (wave >> 1) * 64;
    const int nwg = (int)(gridDim.x * gridDim.y);  // 24*64 = 1536, %8 == 0
    const int lin = (int)(blockIdx.y * gridDim.x + blockIdx.x);
    const int swz = (lin & 7) * (nwg >> 3) + (lin >> 3);
    const int m0 = (swz / (int)gridDim.x) * 128;
    const int n0 = (swz % (int)gridDim.x) * 128;

    f32x4 acc[4][4];
    #pragma unroll
    for (int i = 0; i < 4; i++)
        #pragma unroll
        for (int j = 0; j < 4; j++) acc[i][j] = (f32x4)0.0f;

    // gload geometry (per-lane global addr, wave-uniform LDS dest)
    const int g_r = wave * 32 + (lane >> 3);
    const int g_c = (lane & 7) * 8;
    const u16* ga = (const u16*)A + (size_t)(m0 + g_r) * E_ + g_c;
    const u16* gb = Bt + (size_t)(n0 + g_r) * E_ + g_c;
    // fp32 fallback geometry
    const int srow = tid >> 1;
    const int soff = (tid & 1) * 32;
    const float* abase_f = (const float*)A + (size_t)(m0 + srow) * E_ + soff;

    // prologue: tile 0 -> buf 0 (no barrier; step 0's wait covers it)
    if (isbf) stage_bf64(ga, 0, smem, wave);
    else      stage_a_f32_64(abase_f, 0, smem, srow, soff);
    stage_bf64(gb, 0, smem + 2 * 8192, wave);

    #pragma unroll
    for (int t = 0; t < 16; ++t) {
        const int cur = t & 1;
        if (t < 15) {  // stage tile t+1 -> other buffers (8 gloads in flight)
            const int nxt = cur ^ 1;
            if (isbf) stage_bf64(ga, (t + 1) * 64, smem + nxt * 8192, wave);
            else      stage_a_f32_64(abase_f, (t + 1) * 64, smem + nxt * 8192, srow, soff);
            stage_bf64(gb, (t + 1) * 64, smem + (2 + nxt) * 8192, wave);
        }
        if (isbf) {
            // wait ONLY the previous tile's 8 loads (newest 8 keep flying)
            if (t < 15) asm volatile("s_waitcnt vmcnt(8)" ::: "memory");
            else        asm volatile("s_waitcnt vmcnt(0)" ::: "memory");
            __builtin_amdgcn_sched_barrier(0);
            __builtin_amdgcn_s_barrier();   // collective: tile t complete
            __builtin_amdgcn_sched_barrier(0);
        } else {
            __syncthreads();                // conservative drain (fp32 path)
        }
        __builtin_amdgcn_s_setprio(1);
        mfma_tile64(smem + cur * 8192, smem + (2 + cur) * 8192,
                    acc, wm, wn, lane15, quad);
        __builtin_amdgcn_s_setprio(0);
        if (isbf) {
            __builtin_amdgcn_sched_barrier(0);
            __builtin_amdgcn_s_barrier();   // raw: loads cross freely
            __builtin_amdgcn_sched_barrier(0);
        } else {
            __syncthreads();
        }
    }

    if (n0 < 2048) {
        // q|k half: fp32 + bias into tmp (ldc = 2048)
        #pragma unroll
        for (int j = 0; j < 4; j++) {
            const int col = n0 + wn + j * 16 + lane15;
            const float bb = bias[col];
            #pragma unroll
            for (int i = 0; i < 4; i++) {
                const int row = m0 + wm + i * 16 + quad * 4;
                #pragma unroll
                for (int r = 0; r < 4; r++)
                    Cout[(size_t)(row + r) * 2048 + col] = acc[i][j][r] + bb;
            }
        }
    } else {
        // V half: bf16 + per-head transpose epilogue -> Vt[(b*16+h)*64+d][t]
        __syncthreads();  // all waves' MFMA reads of smem done (full drain)
        u16* c_tile = smem;  // [128][132] = 33792 B, fits
        #pragma unroll
        for (int j = 0; j < 4; j++) {
            const float bb = bias[n0 + wn + j * 16 + lane15];
            #pragma unroll
            for (int i = 0; i < 4; i++)
                #pragma unroll
                for (int r = 0; r < 4; r++)
                    c_tile[(wm + i * 16 + quad * 4 + r) * 132 + wn + j * 16 + lane15] =
                        f2bf(acc[i][j][r] + bb);
        }
        __syncthreads();
        const int b = m0 >> 11, t0 = m0 & 2047;
        const int orow = tid >> 1, half = tid & 1;
        const int n0v = n0 - 2048;
        u16* dst = Vt + ((size_t)b * 1024 + n0v + orow) * T_ + t0 + half * 64;
        #pragma unroll
        for (int c = 0; c < 8; c++) {
            u16x8 o;
            #pragma unroll
            for (int e = 0; e < 8; e++)
                o[e] = c_tile[(half * 64 + c * 8 + e) * 132 + orow];
            *(u16x8*)(dst + c * 8) = o;
        }
    }
}

// ---------------------------------------------------------------------------
// V projection (Path B fallback; reg-staged, unchanged from r3-green)
// ---------------------------------------------------------------------------
__global__ __launch_bounds__(256) void gemm_v_fused_kernel(
    const void* __restrict__ X, const u16* __restrict__ Bt,
    const float* __restrict__ bias, u16* __restrict__ Vt)
{
    __shared__ u16 smem[2 * 128 * 72];  // a | b, later c_tile[128][132]
    u16* a_lds = smem;
    u16* b_lds = smem + 128 * 72;
    const int tid = threadIdx.x;
    const int isbf = block_probe_is_bf16(X, tid);
    const int wave = tid >> 6, lane = tid & 63;
    const int lane15 = lane & 15, quad = lane >> 4;
    const int wm = (wave & 1) * 64, wn = (wave >> 1) * 64;
    const int nwg = (int)(gridDim.x * gridDim.y);
    const int lin = (int)(blockIdx.y * gridDim.x + blockIdx.x);
    const int swz = (lin & 7) * (nwg >> 3) + (lin >> 3);
    const int m0 = (swz / (int)gridDim.x) * 128;
    const int n0 = (swz % (int)gridDim.x) * 128;
    const int srow = tid >> 1;
    const int soff = (tid & 1) * 32;

    f32x4 acc[4][4];
    #pragma unroll
    for (int i = 0; i < 4; i++)
        #pragma unroll
        for (int j = 0; j < 4; j++) acc[i][j] = (f32x4)0.0f;

    const u16* abase_bf = (const u16*)X + (size_t)(m0 + srow) * E_ + soff;
    const float* abase_f = (const float*)X + (size_t)(m0 + srow) * E_ + soff;
    const u16* bbase = Bt + (size_t)(n0 + srow) * E_ + soff;

    u16x8 av[4], bv[4];
    load_a_regs(isbf, abase_bf, abase_f, 0, av);
    load_b_regs(bbase, 0, bv);

    for (int kk = 0; kk < E_; kk += 64) {
        __syncthreads();
        #pragma unroll
        for (int j = 0; j < 4; j++) {
            *(u16x8*)&a_lds[srow * 72 + soff + j * 8] = av[j];
            *(u16x8*)&b_lds[srow * 72 + soff + j * 8] = bv[j];
        }
        __syncthreads();
        if (kk + 64 < E_) {
            load_a_regs(isbf, abase_bf, abase_f, kk + 64, av);
            load_b_regs(bbase, kk + 64, bv);
        }
        #pragma unroll
        for (int ks = 0; ks < 2; ks++) {
            s16x8 af[4], bfr[4];
            #pragma unroll
            for (int i = 0; i < 4; i++)
                af[i] = *(const s16x8*)&a_lds[(wm + i * 16 + lane15) * 72 + ks * 32 + quad * 8];
            #pragma unroll
            for (int j = 0; j < 4; j++)
                bfr[j] = *(const s16x8*)&b_lds[(wn + j * 16 + lane15) * 72 + ks * 32 + quad * 8];
            #pragma unroll
            for (int i = 0; i < 4; i++)
                #pragma unroll
                for (int j = 0; j < 4; j++)
                    acc[i][j] = __builtin_amdgcn_mfma_f32_16x16x32_bf16(af[i], bfr[j], acc[i][j], 0, 0, 0);
        }
    }

    __syncthreads();
    u16* c_tile = smem;  // [128][132]
    #pragma unroll
    for (int j = 0; j < 4; j++) {
        const float bb = bias[n0 + wn + j * 16 + lane15];
        #pragma unroll
        for (int i = 0; i < 4; i++)
            #pragma unroll
            for (int r = 0; r < 4; r++)
                c_tile[(wm + i * 16 + quad * 4 + r) * 132 + wn + j * 16 + lane15] =
                    f2bf(acc[i][j][r] + bb);
    }
    __syncthreads();
    const int b = m0 >> 11, t0 = m0 & 2047;
    const int orow = tid >> 1, half = tid & 1;
    u16* dst = Vt + ((size_t)b * 1024 + n0 + orow) * T_ + t0 + half * 64;
    #pragma unroll
    for (int c = 0; c < 8; c++) {
        u16x8 o;
        #pragma unroll
        for (int e = 0; e < 8; e++)
            o[e] = c_tile[(half * 64 + c * 8 + e) * 132 + orow];
        *(u16x8*)(dst + c * 8) = o;
    }
}

// ---------------------------------------------------------------------------
// quantum_layer on the fused qk projection: tmp row = [q_proj(1024)|k_proj(1024)]
// seg 0 -> key, seg 1 -> qry. out[row][:] = cumprod(cos(in_seg[row][:])).
// ---------------------------------------------------------------------------
__global__ __launch_bounds__(256) void quantum2_kernel(
    const float* __restrict__ in, u16* __restrict__ key, u16* __restrict__ qry)
{
    const int wave = threadIdx.x >> 6, lane = threadIdx.x & 63;
    const int unit = (int)blockIdx.x * 4 + wave;
    const int row = unit >> 1, seg = unit & 1;
    const float* p = in + (size_t)row * 2048 + seg * 1024 + lane * 16;
    float v[16];
    #pragma unroll
    for (int j = 0; j < 16; j += 4) {
        f32x4 t = *(const f32x4*)(p + j);
        v[j] = t[0]; v[j + 1] = t[1]; v[j + 2] = t[2]; v[j + 3] = t[3];
    }
    float pl[16];
    float run = 1.0f;
    #pragma unroll
    for (int j = 0; j < 16; j++) { run *= cosf(v[j]); pl[j] = run; }
    float incl = run;
    #pragma unroll
    for (int off = 1; off < 64; off <<= 1) {
        float t = __shfl_up(incl, off);
        if (lane >= off) incl *= t;
    }
    float pref = __shfl_up(incl, 1);
    if (lane == 0) pref = 1.0f;
    u16x8 o0, o1;
    #pragma unroll
    for (int j = 0; j < 8; j++) {
        o0[j] = f2bf(pref * pl[j]);
        o1[j] = f2bf(pref * pl[j + 8]);
    }
    u16* outp = (seg ? qry : key) + (size_t)row * E_ + lane * 16;
    *(u16x8*)(outp) = o0;
    *(u16x8*)(outp + 8) = o1;
}

// ---------------------------------------------------------------------------
// MFMA flash attention — VERBATIM r9-GREEN version (~108 µs measured).
// ---------------------------------------------------------------------------
__global__ __launch_bounds__(256) void attn_kernel(
    const u16* __restrict__ Qrm, const u16* __restrict__ Krm,
    const u16* __restrict__ Vt, u16* __restrict__ Orm)
{
    __shared__ u16 k_lds[64 * 72];
    __shared__ u16 v_lds[64 * 72];
    __shared__ u16 p_lds[128 * 72];
    const int tid = threadIdx.x;
    const int wave = tid >> 6, lane = tid & 63;
    const int lane15 = lane & 15, quad = lane >> 4;

    const int lin = (int)(blockIdx.x + gridDim.x * blockIdx.y);  // 0..1023
    const int swz = (lin & 7) * 128 + (lin >> 3);
    const int t0 = (swz & 15) * 128;
    const int bh = swz >> 4;
    const int b = bh >> 4, h = bh & 15;

    s16x8 qf[2][2];  // [mt][ks]
    #pragma unroll
    for (int mt = 0; mt < 2; mt++)
        #pragma unroll
        for (int ks = 0; ks < 2; ks++) {
            const u16* src = Qrm
                + (size_t)(b * T_ + t0 + wave * 32 + mt * 16 + lane15) * E_
                + h * 64 + ks * 32 + quad * 8;
            u16x8 t = *(const u16x8*)src;
            u16x8 o;
            #pragma unroll
            for (int e = 0; e < 8; e++) o[e] = f2bf(bf2f(t[e]) * 0.125f);
            qf[mt][ks] = __builtin_bit_cast(s16x8, o);
        }

    f32x4 lsum4[2];
    f32x4 oacc[2][4];
    #pragma unroll
    for (int mt = 0; mt < 2; mt++) {
        lsum4[mt] = (f32x4)0.0f;
        #pragma unroll
        for (int n = 0; n < 4; n++) oacc[mt][n] = (f32x4)0.0f;
    }

    const u16* kbase = Krm + (size_t)(b * T_) * E_ + h * 64;
    const u16* vbase = Vt + (size_t)bh * 64 * T_;
    const int srow = tid >> 2;           // 0..63
    const int soff = (tid & 3) * 16;     // 0/16/32/48

    u16x8 kpre0, kpre1, vpre0, vpre1;
    {
        const u16* ksrc = kbase + (size_t)srow * E_ + soff;
        kpre0 = *(const u16x8*)(ksrc);
        kpre1 = *(const u16x8*)(ksrc + 8);
        const u16* vsrc = vbase + (size_t)srow * T_ + soff;
        vpre0 = *(const u16x8*)(vsrc);
        vpre1 = *(const u16x8*)(vsrc + 8);
    }

    for (int tk0 = 0; tk0 < T_; tk0 += 64) {
        __syncthreads();
        *(u16x8*)&k_lds[srow * 72 + soff]     = kpre0;
        *(u16x8*)&k_lds[srow * 72 + soff + 8] = kpre1;
        *(u16x8*)&v_lds[srow * 72 + soff]     = vpre0;
        *(u16x8*)&v_lds[srow * 72 + soff + 8] = vpre1;
        __syncthreads();

        if (tk0 + 64 < T_) {
            const u16* ksrc = kbase + (size_t)(tk0 + 64 + srow) * E_ + soff;
            kpre0 = *(const u16x8*)(ksrc);
            kpre1 = *(const u16x8*)(ksrc + 8);
            const u16* vsrc = vbase + (size_t)srow * T_ + tk0 + 64 + soff;
            vpre0 = *(const u16x8*)(vsrc);
            vpre1 = *(const u16x8*)(vsrc + 8);
        }

        f32x4 sacc[2][4];
        #pragma unroll
        for (int mt = 0; mt < 2; mt++)
            #pragma unroll
            for (int j = 0; j < 4; j++) sacc[mt][j] = (f32x4)0.0f;
        #pragma unroll
        for (int ks = 0; ks < 2; ks++) {
            s16x8 kb[4];
            #pragma unroll
            for (int j = 0; j < 4; j++)
                kb[j] = *(const s16x8*)&k_lds[(j * 16 + lane15) * 72 + ks * 32 + quad * 8];
            #pragma unroll
            for (int mt = 0; mt < 2; mt++)
                #pragma unroll
                for (int j = 0; j < 4; j++)
                    sacc[mt][j] = __builtin_amdgcn_mfma_f32_16x16x32_bf16(
                        kb[j], qf[mt][ks], sacc[mt][j], 0, 0, 0);
        }

        #pragma unroll
        for (int mt = 0; mt < 2; mt++)
            #pragma unroll
            for (int j = 0; j < 4; j++) {
                const f32x4 s = sacc[mt][j];
                const float p0 = __expf(s[0]);
                const float p1 = __expf(s[1]);
                const float p2 = __expf(s[2]);
                const float p3 = __expf(s[3]);
                lsum4[mt][0] += p0; lsum4[mt][1] += p1;
                lsum4[mt][2] += p2; lsum4[mt][3] += p3;
                u32x2 w;
                w[0] = pk2(p0, p1);
                w[1] = pk2(p2, p3);
                *(u32x2*)&p_lds[(wave * 32 + mt * 16 + lane15) * 72 + j * 16 + quad * 4] = w;
            }

        #pragma unroll
        for (int ks = 0; ks < 2; ks++) {
            s16x8 pa[2], vb[4];
            #pragma unroll
            for (int mt = 0; mt < 2; mt++)
                pa[mt] = *(const s16x8*)&p_lds[(wave * 32 + mt * 16 + lane15) * 72 + ks * 32 + quad * 8];
            #pragma unroll
            for (int n = 0; n < 4; n++)
                vb[n] = *(const s16x8*)&v_lds[(n * 16 + lane15) * 72 + ks * 32 + quad * 8];
            #pragma unroll
            for (int mt = 0; mt < 2; mt++)
                #pragma unroll
                for (int n = 0; n < 4; n++)
                    oacc[mt][n] = __builtin_amdgcn_mfma_f32_16x16x32_bf16(
                        pa[mt], vb[n], oacc[mt][n], 0, 0, 0);
        }
    }

    #pragma unroll
    for (int mt = 0; mt < 2; mt++) {
        float l = lsum4[mt][0] + lsum4[mt][1] + lsum4[mt][2] + lsum4[mt][3];
        l += __shfl_xor(l, 16);
        l += __shfl_xor(l, 32);
        #pragma unroll
        for (int r = 0; r < 4; r++) {
            const float lr = __shfl(l, quad * 4 + r);
            const float inv = 1.0f / lr;
            const size_t row = (size_t)(b * T_ + t0 + wave * 32 + mt * 16 + quad * 4 + r);
            #pragma unroll
            for (int n = 0; n < 4; n++)
                Orm[row * E_ + h * 64 + n * 16 + lane15] = f2bf(oacc[mt][n][r] * inv);
        }
    }
}

// ---------------------------------------------------------------------------
// Workspace (MB offsets). Common: [0,2) wt_o; [2,+16K) biasf; [3,9) wt_qkv
// (Wq^T|Wk^T|Wv^T); [9,25) key; [25,41) qry.
// Path A (ws >= 121 MB): vt [41,57); tmp fp32 8192x2048 [57,121);
//   orm [57,73) overlays tmp after quantum.
// Path B (fallback, peak 73 MB): tmp fp32 4096x2048 [41,73);
//   vt [41,57) after tmp dead; orm [57,73).
// ---------------------------------------------------------------------------
extern "C" void kernel_launch(void* const* d_in, const int* in_sizes, int n_in,
                              void* d_out, int out_size, void* d_ws, size_t ws_size,
                              hipStream_t stream) {
    (void)in_sizes; (void)n_in; (void)out_size;
    const void* x  = d_in[0];
    const void* Wq = d_in[1];
    const void* bq = d_in[2];
    const void* Wk = d_in[3];
    const void* bk = d_in[4];
    const void* Wv = d_in[5];
    const void* bv = d_in[6];
    const void* Wo = d_in[7];
    const void* bo = d_in[8];

    char* ws = (char*)d_ws;
    const size_t MB = 1024 * 1024;
    u16*   wt_o   = (u16*)(ws);
    float* biasf  = (float*)(ws + 2 * MB);
    u16*   wt_qkv = (u16*)(ws + 3 * MB);  // 3072 x 1024
    u16*   key    = (u16*)(ws + 9 * MB);
    u16*   qry    = (u16*)(ws + 25 * MB);

    transpose_w4_kernel<<<dim3(16, 16, 4), dim3(64, 4), 0, stream>>>(
        Wq, Wk, Wv, Wo,
        wt_qkv, wt_qkv + 1024 * 1024, wt_qkv + 2 * 1024 * 1024, wt_o, x);
    convert_bias_kernel<<<dim3(4, 4), 256, 0, stream>>>(
        bq, bk, bv, bo, biasf, x);

    if (ws_size >= (size_t)121 * MB) {
        // Path A: one fused QKV GEMM (1536 blocks; 64KB LDS -> 2 blocks/CU)
        u16*   vt  = (u16*)(ws + 41 * MB);
        float* tmp = (float*)(ws + 57 * MB);
        u16*   orm = (u16*)(ws + 57 * MB);
        gemm_qkv_kernel<<<dim3(24, 64), 256, 0, stream>>>(
            x, wt_qkv, biasf, tmp, vt);
        quantum2_kernel<<<4096, 256, 0, stream>>>(tmp, key, qry);
        attn_kernel<<<dim3(16, 64), 256, 0, stream>>>(qry, key, vt, orm);
        gemm_f32out_kernel<<<dim3(8, 64), 256, 0, stream>>>(
            orm, 1, 0, wt_o, biasf + 3 * 1024, (float*)d_out, 1024);
    } else {
        // Path B: QK fused x2 + separate V (all reg-staged pipelines)
        float* tmp = (float*)(ws + 41 * MB);
        u16*   vt  = (u16*)(ws + 41 * MB);
        u16*   orm = (u16*)(ws + 57 * MB);
        for (int hh = 0; hh < 2; hh++) {
            gemm_f32out_kernel<<<dim3(16, 32), 256, 0, stream>>>(
                x, -1, hh * 4096, wt_qkv, biasf, tmp, 2048);
            quantum2_kernel<<<2048, 256, 0, stream>>>(
                tmp, key + (size_t)hh * 4096 * E_, qry + (size_t)hh * 4096 * E_);
        }
        gemm_v_fused_kernel<<<dim3(8, 64), 256, 0, stream>>>(
            x, wt_qkv + 2 * 1024 * 1024, biasf + 2 * 1024, vt);
        attn_kernel<<<dim3(16, 64), 256, 0, stream>>>(qry, key, vt, orm);
        gemm_f32out_kernel<<<dim3(8, 64), 256, 0, stream>>>(
            orm, 1, 0, wt_o, biasf + 3 * 1024, (float*)d_out, 1024);
    }
}

// Round 14
// 371.427 us; speedup vs baseline: 1.1056x; 1.1056x over previous
//
#include <hip/hip_runtime.h>
#include <hip/hip_bf16.h>
#include <stdint.h>

// Problem constants
#define B_ 4
#define T_ 2048
#define E_ 1024
#define H_ 16
#define D_ 64
#define M_ (B_ * T_)  // 8192 rows

typedef unsigned short u16;
typedef unsigned int u32;
typedef short s16x8 __attribute__((ext_vector_type(8)));
typedef unsigned short u16x8 __attribute__((ext_vector_type(8)));
typedef float f32x4 __attribute__((ext_vector_type(4)));
typedef unsigned int u32x2 __attribute__((ext_vector_type(2)));

// LDS pitch 72 u16 = 144 B: 16B-aligned rows (ds_*_b128), ~2-way conflicts.
// HARD RULE (r6/r8/r11/r13 forensics): static LDS request <= 65536 B.
#define LP_ 72

__device__ __forceinline__ u16 f2bf(float f) {
    __hip_bfloat16 h = __float2bfloat16(f);
    return __builtin_bit_cast(u16, h);
}
__device__ __forceinline__ float bf2f(u16 u) {
    unsigned int v = ((unsigned int)u) << 16;
    return __builtin_bit_cast(float, v);
}
__device__ __forceinline__ u32 pk2(float a, float b) {
    return (u32)f2bf(a) | ((u32)f2bf(b) << 16);
}

// ---------------------------------------------------------------------------
// Dtype probe (block-cooperative, 256 threads).
// ---------------------------------------------------------------------------
__device__ __forceinline__ int block_probe_is_bf16(const void* x, int tid) {
    const u16* p = (const u16*)x;
    u16 u = p[tid];
    int e = (u >> 7) & 0xFF;
    int ok = ((u & 0x7FFF) == 0 || (e >= 103 && e <= 133)) ? 1 : 0;
    return (__syncthreads_count(ok) >= 240) ? 1 : 0;
}

// ---------------------------------------------------------------------------
// GEMM building blocks (128x128 tile, BK=64, reg-staged, pitch-72 LDS)
// per-thread staging: srow = tid>>1 (0..127), soff = (tid&1)*32; 4 x u16x8.
// ---------------------------------------------------------------------------
__device__ __forceinline__ void load_a_regs(
    int a_bf, const u16* abase_bf, const float* abase_f, int kk, u16x8 (&av)[4])
{
    if (a_bf) {
        #pragma unroll
        for (int j = 0; j < 4; j++) av[j] = *(const u16x8*)(abase_bf + kk + j * 8);
    } else {
        #pragma unroll
        for (int j = 0; j < 4; j++) {
            f32x4 t0 = *(const f32x4*)(abase_f + kk + j * 8);
            f32x4 t1 = *(const f32x4*)(abase_f + kk + j * 8 + 4);
            u16x8 o;
            #pragma unroll
            for (int e = 0; e < 4; e++) { o[e] = f2bf(t0[e]); o[4 + e] = f2bf(t1[e]); }
            av[j] = o;
        }
    }
}
__device__ __forceinline__ void load_b_regs(const u16* bbase, int kk, u16x8 (&bv)[4]) {
    #pragma unroll
    for (int j = 0; j < 4; j++) bv[j] = *(const u16x8*)(bbase + kk + j * 8);
}
__device__ __forceinline__ void write_lds72(
    u16* l, int srow, int soff, const u16x8 (&v)[4])
{
    #pragma unroll
    for (int j = 0; j < 4; j++)
        *(u16x8*)&l[srow * LP_ + soff + j * 8] = v[j];
}
__device__ __forceinline__ void mfma_tile72(
    const u16* al, const u16* bl, f32x4 (&acc)[4][4],
    int wm, int wn, int lane15, int quad)
{
    #pragma unroll
    for (int ks = 0; ks < 2; ks++) {
        s16x8 af[4], bfr[4];
        #pragma unroll
        for (int i = 0; i < 4; i++)
            af[i] = *(const s16x8*)&al[(wm + i * 16 + lane15) * LP_ + ks * 32 + quad * 8];
        #pragma unroll
        for (int j = 0; j < 4; j++)
            bfr[j] = *(const s16x8*)&bl[(wn + j * 16 + lane15) * LP_ + ks * 32 + quad * 8];
        #pragma unroll
        for (int i = 0; i < 4; i++)
            #pragma unroll
            for (int j = 0; j < 4; j++)
                acc[i][j] = __builtin_amdgcn_mfma_f32_16x16x32_bf16(af[i], bfr[j], acc[i][j], 0, 0, 0);
    }
}

// ---------------------------------------------------------------------------
// bf16 transpose for FOUR weight matrices in one launch: W[k][n] -> Wt[n][k]
// ---------------------------------------------------------------------------
__global__ __launch_bounds__(256) void transpose_w4_kernel(
    const void* __restrict__ w0, const void* __restrict__ w1,
    const void* __restrict__ w2, const void* __restrict__ w3,
    u16* __restrict__ o0, u16* __restrict__ o1,
    u16* __restrict__ o2, u16* __restrict__ o3,
    const void* __restrict__ xprobe)
{
    __shared__ u16 th[64][66];
    const int x = threadIdx.x, y = threadIdx.y;
    const int isbf = block_probe_is_bf16(xprobe, y * 64 + x);
    const int z = (int)blockIdx.z;
    const void* in = (z == 0) ? w0 : (z == 1) ? w1 : (z == 2) ? w2 : w3;
    u16* o = (z == 0) ? o0 : (z == 1) ? o1 : (z == 2) ? o2 : o3;
    const int r0 = blockIdx.y * 64;
    const int c0 = blockIdx.x * 64;
    #pragma unroll
    for (int j = 0; j < 16; j++) {
        const size_t idx = (size_t)(r0 + y * 16 + j) * E_ + c0 + x;
        float v = isbf ? bf2f(((const u16*)in)[idx]) : ((const float*)in)[idx];
        th[y * 16 + j][x] = f2bf(v);
    }
    __syncthreads();
    #pragma unroll
    for (int j = 0; j < 16; j++)
        o[(size_t)(c0 + y * 16 + j) * E_ + r0 + x] = th[x][y * 16 + j];
}

// ---------------------------------------------------------------------------
// All four biases -> fp32 (bq|bk|bv|bo)
// ---------------------------------------------------------------------------
__global__ __launch_bounds__(256) void convert_bias_kernel(
    const void* __restrict__ bq, const void* __restrict__ bk,
    const void* __restrict__ bv, const void* __restrict__ bo,
    float* __restrict__ outb, const void* __restrict__ xprobe)
{
    const int isbf = block_probe_is_bf16(xprobe, threadIdx.x);
    const int i = blockIdx.x * 256 + threadIdx.x;  // < 1024
    const int w = blockIdx.y;
    const void* p = (w == 0) ? bq : (w == 1) ? bk : (w == 2) ? bv : bo;
    float v = isbf ? bf2f(((const u16*)p)[i]) : ((const float*)p)[i];
    outb[w * 1024 + i] = v;
}

// ---------------------------------------------------------------------------
// bf16 MFMA GEMM, fp32 out. r9-GREEN two-barrier reg-staged prefetch loop.
// ---------------------------------------------------------------------------
__global__ __launch_bounds__(256) void gemm_f32out_kernel(
    const void* __restrict__ A, int a_mode, int m_base,
    const u16* __restrict__ Bt, const float* __restrict__ bias,
    float* __restrict__ Cout, int ldc)
{
    __shared__ u16 a_lds[128 * LP_];
    __shared__ u16 b_lds[128 * LP_];
    const int tid = threadIdx.x;
    const int isbf = block_probe_is_bf16(A, tid);
    const int a_bf = (a_mode < 0) ? isbf : a_mode;
    const int wave = tid >> 6, lane = tid & 63;
    const int lane15 = lane & 15, quad = lane >> 4;
    const int wm = (wave & 1) * 64, wn = (wave >> 1) * 64;
    const int nwg = (int)(gridDim.x * gridDim.y);
    const int lin = (int)(blockIdx.y * gridDim.x + blockIdx.x);
    const int swz = (lin & 7) * (nwg >> 3) + (lin >> 3);
    const int m0 = (swz / (int)gridDim.x) * 128;
    const int n0 = (swz % (int)gridDim.x) * 128;
    const int srow = tid >> 1;
    const int soff = (tid & 1) * 32;

    f32x4 acc[4][4];
    #pragma unroll
    for (int i = 0; i < 4; i++)
        #pragma unroll
        for (int j = 0; j < 4; j++) acc[i][j] = (f32x4)0.0f;

    const u16* abase_bf = (const u16*)A + (size_t)(m_base + m0 + srow) * E_ + soff;
    const float* abase_f = (const float*)A + (size_t)(m_base + m0 + srow) * E_ + soff;
    const u16* bbase = Bt + (size_t)(n0 + srow) * E_ + soff;

    u16x8 av[4], bv[4];
    load_a_regs(a_bf, abase_bf, abase_f, 0, av);
    load_b_regs(bbase, 0, bv);

    for (int kk = 0; kk < E_; kk += 64) {
        __syncthreads();   // previous tile's MFMA reads done
        write_lds72(a_lds, srow, soff, av);
        write_lds72(b_lds, srow, soff, bv);
        __syncthreads();   // staging visible
        if (kk + 64 < E_) {  // prefetch next tile; in flight across MFMA
            load_a_regs(a_bf, abase_bf, abase_f, kk + 64, av);
            load_b_regs(bbase, kk + 64, bv);
        }
        mfma_tile72(a_lds, b_lds, acc, wm, wn, lane15, quad);
    }

    #pragma unroll
    for (int j = 0; j < 4; j++) {
        const int col = n0 + wn + j * 16 + lane15;
        const float bb = bias[col];
        #pragma unroll
        for (int i = 0; i < 4; i++) {
            const int row = m0 + wm + i * 16 + quad * 4;
            #pragma unroll
            for (int r = 0; r < 4; r++)
                Cout[(size_t)(row + r) * ldc + col] = acc[i][j][r] + bb;
        }
    }
}

// ---------------------------------------------------------------------------
// FUSED Q|K|V projection GEMM (Path A) — r9-GREEN reg-staged two-barrier
// structure (151 µs measured). Ledger: 5 structures tried at this shape
// (gload single-buf 150 / THIS 151 / depth-2 regs 151 / 2-step-unroll 180 /
// counted-vmcnt 179) — 2-barrier-family ceiling ~342 TF == m102 shape curve.
// ---------------------------------------------------------------------------
__global__ __launch_bounds__(256) void gemm_qkv_kernel(
    const void* __restrict__ A, const u16* __restrict__ Bt,
    const float* __restrict__ bias, float* __restrict__ Cout,
    u16* __restrict__ Vt)
{
    __shared__ u16 smem[2 * 128 * LP_];  // a | b; c_tile[128][132] overlays
    u16* a_lds = smem;
    u16* b_lds = smem + 128 * LP_;
    const int tid = threadIdx.x;
    const int isbf = block_probe_is_bf16(A, tid);
    const int wave = tid >> 6, lane = tid & 63;
    const int lane15 = lane & 15, quad = lane >> 4;
    const int wm = (wave & 1) * 64, wn = (wave >> 1) * 64;
    const int nwg = (int)(gridDim.x * gridDim.y);  // 24*64 = 1536, %8 == 0
    const int lin = (int)(blockIdx.y * gridDim.x + blockIdx.x);
    const int swz = (lin & 7) * (nwg >> 3) + (lin >> 3);
    const int m0 = (swz / (int)gridDim.x) * 128;
    const int n0 = (swz % (int)gridDim.x) * 128;
    const int srow = tid >> 1;
    const int soff = (tid & 1) * 32;

    f32x4 acc[4][4];
    #pragma unroll
    for (int i = 0; i < 4; i++)
        #pragma unroll
        for (int j = 0; j < 4; j++) acc[i][j] = (f32x4)0.0f;

    const u16* abase_bf = (const u16*)A + (size_t)(m0 + srow) * E_ + soff;
    const float* abase_f = (const float*)A + (size_t)(m0 + srow) * E_ + soff;
    const u16* bbase = Bt + (size_t)(n0 + srow) * E_ + soff;

    u16x8 av[4], bv[4];
    load_a_regs(isbf, abase_bf, abase_f, 0, av);
    load_b_regs(bbase, 0, bv);

    for (int kk = 0; kk < E_; kk += 64) {
        __syncthreads();
        write_lds72(a_lds, srow, soff, av);
        write_lds72(b_lds, srow, soff, bv);
        __syncthreads();
        if (kk + 64 < E_) {
            load_a_regs(isbf, abase_bf, abase_f, kk + 64, av);
            load_b_regs(bbase, kk + 64, bv);
        }
        mfma_tile72(a_lds, b_lds, acc, wm, wn, lane15, quad);
    }

    if (n0 < 2048) {
        // q|k half: fp32 + bias into tmp (ldc = 2048)
        #pragma unroll
        for (int j = 0; j < 4; j++) {
            const int col = n0 + wn + j * 16 + lane15;
            const float bb = bias[col];
            #pragma unroll
            for (int i = 0; i < 4; i++) {
                const int row = m0 + wm + i * 16 + quad * 4;
                #pragma unroll
                for (int r = 0; r < 4; r++)
                    Cout[(size_t)(row + r) * 2048 + col] = acc[i][j][r] + bb;
            }
        }
    } else {
        // V half: bf16 + per-head transpose epilogue -> Vt[(b*16+h)*64+d][t]
        __syncthreads();  // all waves' MFMA reads of a_lds/b_lds done
        u16* c_tile = smem;  // [128][132]
        #pragma unroll
        for (int j = 0; j < 4; j++) {
            const float bb = bias[n0 + wn + j * 16 + lane15];
            #pragma unroll
            for (int i = 0; i < 4; i++)
                #pragma unroll
                for (int r = 0; r < 4; r++)
                    c_tile[(wm + i * 16 + quad * 4 + r) * 132 + wn + j * 16 + lane15] =
                        f2bf(acc[i][j][r] + bb);
        }
        __syncthreads();
        const int b = m0 >> 11, t0 = m0 & 2047;
        const int orow = tid >> 1, half = tid & 1;
        const int n0v = n0 - 2048;
        u16* dst = Vt + ((size_t)b * 1024 + n0v + orow) * T_ + t0 + half * 64;
        #pragma unroll
        for (int c = 0; c < 8; c++) {
            u16x8 o;
            #pragma unroll
            for (int e = 0; e < 8; e++)
                o[e] = c_tile[(half * 64 + c * 8 + e) * 132 + orow];
            *(u16x8*)(dst + c * 8) = o;
        }
    }
}

// ---------------------------------------------------------------------------
// V projection (Path B fallback; reg-staged, unchanged from r3-green)
// ---------------------------------------------------------------------------
__global__ __launch_bounds__(256) void gemm_v_fused_kernel(
    const void* __restrict__ X, const u16* __restrict__ Bt,
    const float* __restrict__ bias, u16* __restrict__ Vt)
{
    __shared__ u16 smem[2 * 128 * 72];  // a | b, later c_tile[128][132]
    u16* a_lds = smem;
    u16* b_lds = smem + 128 * 72;
    const int tid = threadIdx.x;
    const int isbf = block_probe_is_bf16(X, tid);
    const int wave = tid >> 6, lane = tid & 63;
    const int lane15 = lane & 15, quad = lane >> 4;
    const int wm = (wave & 1) * 64, wn = (wave >> 1) * 64;
    const int nwg = (int)(gridDim.x * gridDim.y);
    const int lin = (int)(blockIdx.y * gridDim.x + blockIdx.x);
    const int swz = (lin & 7) * (nwg >> 3) + (lin >> 3);
    const int m0 = (swz / (int)gridDim.x) * 128;
    const int n0 = (swz % (int)gridDim.x) * 128;
    const int srow = tid >> 1;
    const int soff = (tid & 1) * 32;

    f32x4 acc[4][4];
    #pragma unroll
    for (int i = 0; i < 4; i++)
        #pragma unroll
        for (int j = 0; j < 4; j++) acc[i][j] = (f32x4)0.0f;

    const u16* abase_bf = (const u16*)X + (size_t)(m0 + srow) * E_ + soff;
    const float* abase_f = (const float*)X + (size_t)(m0 + srow) * E_ + soff;
    const u16* bbase = Bt + (size_t)(n0 + srow) * E_ + soff;

    u16x8 av[4], bv[4];
    load_a_regs(isbf, abase_bf, abase_f, 0, av);
    load_b_regs(bbase, 0, bv);

    for (int kk = 0; kk < E_; kk += 64) {
        __syncthreads();
        #pragma unroll
        for (int j = 0; j < 4; j++) {
            *(u16x8*)&a_lds[srow * 72 + soff + j * 8] = av[j];
            *(u16x8*)&b_lds[srow * 72 + soff + j * 8] = bv[j];
        }
        __syncthreads();
        if (kk + 64 < E_) {
            load_a_regs(isbf, abase_bf, abase_f, kk + 64, av);
            load_b_regs(bbase, kk + 64, bv);
        }
        #pragma unroll
        for (int ks = 0; ks < 2; ks++) {
            s16x8 af[4], bfr[4];
            #pragma unroll
            for (int i = 0; i < 4; i++)
                af[i] = *(const s16x8*)&a_lds[(wm + i * 16 + lane15) * 72 + ks * 32 + quad * 8];
            #pragma unroll
            for (int j = 0; j < 4; j++)
                bfr[j] = *(const s16x8*)&b_lds[(wn + j * 16 + lane15) * 72 + ks * 32 + quad * 8];
            #pragma unroll
            for (int i = 0; i < 4; i++)
                #pragma unroll
                for (int j = 0; j < 4; j++)
                    acc[i][j] = __builtin_amdgcn_mfma_f32_16x16x32_bf16(af[i], bfr[j], acc[i][j], 0, 0, 0);
        }
    }

    __syncthreads();
    u16* c_tile = smem;  // [128][132]
    #pragma unroll
    for (int j = 0; j < 4; j++) {
        const float bb = bias[n0 + wn + j * 16 + lane15];
        #pragma unroll
        for (int i = 0; i < 4; i++)
            #pragma unroll
            for (int r = 0; r < 4; r++)
                c_tile[(wm + i * 16 + quad * 4 + r) * 132 + wn + j * 16 + lane15] =
                    f2bf(acc[i][j][r] + bb);
    }
    __syncthreads();
    const int b = m0 >> 11, t0 = m0 & 2047;
    const int orow = tid >> 1, half = tid & 1;
    u16* dst = Vt + ((size_t)b * 1024 + n0 + orow) * T_ + t0 + half * 64;
    #pragma unroll
    for (int c = 0; c < 8; c++) {
        u16x8 o;
        #pragma unroll
        for (int e = 0; e < 8; e++)
            o[e] = c_tile[(half * 64 + c * 8 + e) * 132 + orow];
        *(u16x8*)(dst + c * 8) = o;
    }
}

// ---------------------------------------------------------------------------
// quantum_layer on the fused qk projection: tmp row = [q_proj(1024)|k_proj(1024)]
// seg 0 -> key, seg 1 -> qry. out[row][:] = cumprod(cos(in_seg[row][:])).
// ---------------------------------------------------------------------------
__global__ __launch_bounds__(256) void quantum2_kernel(
    const float* __restrict__ in, u16* __restrict__ key, u16* __restrict__ qry)
{
    const int wave = threadIdx.x >> 6, lane = threadIdx.x & 63;
    const int unit = (int)blockIdx.x * 4 + wave;
    const int row = unit >> 1, seg = unit & 1;
    const float* p = in + (size_t)row * 2048 + seg * 1024 + lane * 16;
    float v[16];
    #pragma unroll
    for (int j = 0; j < 16; j += 4) {
        f32x4 t = *(const f32x4*)(p + j);
        v[j] = t[0]; v[j + 1] = t[1]; v[j + 2] = t[2]; v[j + 3] = t[3];
    }
    float pl[16];
    float run = 1.0f;
    #pragma unroll
    for (int j = 0; j < 16; j++) { run *= cosf(v[j]); pl[j] = run; }
    float incl = run;
    #pragma unroll
    for (int off = 1; off < 64; off <<= 1) {
        float t = __shfl_up(incl, off);
        if (lane >= off) incl *= t;
    }
    float pref = __shfl_up(incl, 1);
    if (lane == 0) pref = 1.0f;
    u16x8 o0, o1;
    #pragma unroll
    for (int j = 0; j < 8; j++) {
        o0[j] = f2bf(pref * pl[j]);
        o1[j] = f2bf(pref * pl[j + 8]);
    }
    u16* outp = (seg ? qry : key) + (size_t)row * E_ + lane * 16;
    *(u16x8*)(outp) = o0;
    *(u16x8*)(outp + 8) = o1;
}

// ---------------------------------------------------------------------------
// MFMA flash attention — r9-green base + ONES-MFMA ROW-SUM (register-level
// only; r8's NaN is attributed to the gemm 73728B LDS bug, not this change).
// P = __expf(S), exact 0.125 prescale — bit-identical P to green. lsum is
// now mfma(P, ones): with all-ones B every column holds the A-row sum, in
// oacc's exact row layout -> removes 32 VALU adds/chunk AND the epilogue
// shuffles. Denominator sums the SAME bf16 P that feeds PV (consistent).
// ---------------------------------------------------------------------------
__global__ __launch_bounds__(256) void attn_kernel(
    const u16* __restrict__ Qrm, const u16* __restrict__ Krm,
    const u16* __restrict__ Vt, u16* __restrict__ Orm)
{
    __shared__ u16 k_lds[64 * 72];
    __shared__ u16 v_lds[64 * 72];
    __shared__ u16 p_lds[128 * 72];
    const int tid = threadIdx.x;
    const int wave = tid >> 6, lane = tid & 63;
    const int lane15 = lane & 15, quad = lane >> 4;

    const int lin = (int)(blockIdx.x + gridDim.x * blockIdx.y);  // 0..1023
    const int swz = (lin & 7) * 128 + (lin >> 3);
    const int t0 = (swz & 15) * 128;
    const int bh = swz >> 4;
    const int b = bh >> 4, h = bh & 15;

    // ones fragment (bf16 1.0) for the row-sum MFMA
    u16x8 ov;
    #pragma unroll
    for (int e = 0; e < 8; e++) ov[e] = 0x3F80;
    const s16x8 ones = __builtin_bit_cast(s16x8, ov);

    // Q fragments (B-operand of swapped QK^T), prescaled by exact 1/8
    s16x8 qf[2][2];  // [mt][ks]
    #pragma unroll
    for (int mt = 0; mt < 2; mt++)
        #pragma unroll
        for (int ks = 0; ks < 2; ks++) {
            const u16* src = Qrm
                + (size_t)(b * T_ + t0 + wave * 32 + mt * 16 + lane15) * E_
                + h * 64 + ks * 32 + quad * 8;
            u16x8 t = *(const u16x8*)src;
            u16x8 o;
            #pragma unroll
            for (int e = 0; e < 8; e++) o[e] = f2bf(bf2f(t[e]) * 0.125f);
            qf[mt][ks] = __builtin_bit_cast(s16x8, o);
        }

    f32x4 lsum[2];
    f32x4 oacc[2][4];
    #pragma unroll
    for (int mt = 0; mt < 2; mt++) {
        lsum[mt] = (f32x4)0.0f;
        #pragma unroll
        for (int n = 0; n < 4; n++) oacc[mt][n] = (f32x4)0.0f;
    }

    const u16* kbase = Krm + (size_t)(b * T_) * E_ + h * 64;
    const u16* vbase = Vt + (size_t)bh * 64 * T_;
    const int srow = tid >> 2;           // 0..63
    const int soff = (tid & 3) * 16;     // 0/16/32/48

    u16x8 kpre0, kpre1, vpre0, vpre1;
    {
        const u16* ksrc = kbase + (size_t)srow * E_ + soff;
        kpre0 = *(const u16x8*)(ksrc);
        kpre1 = *(const u16x8*)(ksrc + 8);
        const u16* vsrc = vbase + (size_t)srow * T_ + soff;
        vpre0 = *(const u16x8*)(vsrc);
        vpre1 = *(const u16x8*)(vsrc + 8);
    }

    for (int tk0 = 0; tk0 < T_; tk0 += 64) {
        __syncthreads();
        *(u16x8*)&k_lds[srow * 72 + soff]     = kpre0;
        *(u16x8*)&k_lds[srow * 72 + soff + 8] = kpre1;
        *(u16x8*)&v_lds[srow * 72 + soff]     = vpre0;
        *(u16x8*)&v_lds[srow * 72 + soff + 8] = vpre1;
        __syncthreads();

        if (tk0 + 64 < T_) {
            const u16* ksrc = kbase + (size_t)(tk0 + 64 + srow) * E_ + soff;
            kpre0 = *(const u16x8*)(ksrc);
            kpre1 = *(const u16x8*)(ksrc + 8);
            const u16* vsrc = vbase + (size_t)srow * T_ + tk0 + 64 + soff;
            vpre0 = *(const u16x8*)(vsrc);
            vpre1 = *(const u16x8*)(vsrc + 8);
        }

        // S^T = K (Q/8)^T : lane holds S[q=lane15][kv=j*16+quad*4+r]
        f32x4 sacc[2][4];
        #pragma unroll
        for (int mt = 0; mt < 2; mt++)
            #pragma unroll
            for (int j = 0; j < 4; j++) sacc[mt][j] = (f32x4)0.0f;
        #pragma unroll
        for (int ks = 0; ks < 2; ks++) {
            s16x8 kb[4];
            #pragma unroll
            for (int j = 0; j < 4; j++)
                kb[j] = *(const s16x8*)&k_lds[(j * 16 + lane15) * 72 + ks * 32 + quad * 8];
            #pragma unroll
            for (int mt = 0; mt < 2; mt++)
                #pragma unroll
                for (int j = 0; j < 4; j++)
                    sacc[mt][j] = __builtin_amdgcn_mfma_f32_16x16x32_bf16(
                        kb[j], qf[mt][ks], sacc[mt][j], 0, 0, 0);
        }

        // P = exp(S): pack bf16 pairs; b64 write to wave-private p_lds rows
        // (no VALU row-sum — lsum comes from the ones-MFMA below)
        #pragma unroll
        for (int mt = 0; mt < 2; mt++)
            #pragma unroll
            for (int j = 0; j < 4; j++) {
                const f32x4 s = sacc[mt][j];
                u32x2 w;
                w[0] = pk2(__expf(s[0]), __expf(s[1]));
                w[1] = pk2(__expf(s[2]), __expf(s[3]));
                *(u32x2*)&p_lds[(wave * 32 + mt * 16 + lane15) * 72 + j * 16 + quad * 4] = w;
            }

        // O += P V ; lsum += P @ ones (row-sum in oacc layout, MFMA pipe)
        #pragma unroll
        for (int ks = 0; ks < 2; ks++) {
            s16x8 pa[2], vb[4];
            #pragma unroll
            for (int mt = 0; mt < 2; mt++)
                pa[mt] = *(const s16x8*)&p_lds[(wave * 32 + mt * 16 + lane15) * 72 + ks * 32 + quad * 8];
            #pragma unroll
            for (int n = 0; n < 4; n++)
                vb[n] = *(const s16x8*)&v_lds[(n * 16 + lane15) * 72 + ks * 32 + quad * 8];
            #pragma unroll
            for (int mt = 0; mt < 2; mt++) {
                lsum[mt] = __builtin_amdgcn_mfma_f32_16x16x32_bf16(
                    pa[mt], ones, lsum[mt], 0, 0, 0);
                #pragma unroll
                for (int n = 0; n < 4; n++)
                    oacc[mt][n] = __builtin_amdgcn_mfma_f32_16x16x32_bf16(
                        pa[mt], vb[n], oacc[mt][n], 0, 0, 0);
            }
        }
    }

    // epilogue: lsum[mt][r] = row-sum for row quad*4+r (oacc layout) —
    // normalize directly, no cross-lane ops.
    #pragma unroll
    for (int mt = 0; mt < 2; mt++) {
        #pragma unroll
        for (int r = 0; r < 4; r++) {
            const float inv = 1.0f / lsum[mt][r];
            const size_t row = (size_t)(b * T_ + t0 + wave * 32 + mt * 16 + quad * 4 + r);
            #pragma unroll
            for (int n = 0; n < 4; n++)
                Orm[row * E_ + h * 64 + n * 16 + lane15] = f2bf(oacc[mt][n][r] * inv);
        }
    }
}

// ---------------------------------------------------------------------------
// Workspace (MB offsets). Common: [0,2) wt_o; [2,+16K) biasf; [3,9) wt_qkv
// (Wq^T|Wk^T|Wv^T); [9,25) key; [25,41) qry.
// Path A (ws >= 121 MB): vt [41,57); tmp fp32 8192x2048 [57,121);
//   orm [57,73) overlays tmp after quantum.
// Path B (fallback, peak 73 MB): tmp fp32 4096x2048 [41,73);
//   vt [41,57) after tmp dead; orm [57,73).
// ---------------------------------------------------------------------------
extern "C" void kernel_launch(void* const* d_in, const int* in_sizes, int n_in,
                              void* d_out, int out_size, void* d_ws, size_t ws_size,
                              hipStream_t stream) {
    (void)in_sizes; (void)n_in; (void)out_size;
    const void* x  = d_in[0];
    const void* Wq = d_in[1];
    const void* bq = d_in[2];
    const void* Wk = d_in[3];
    const void* bk = d_in[4];
    const void* Wv = d_in[5];
    const void* bv = d_in[6];
    const void* Wo = d_in[7];
    const void* bo = d_in[8];

    char* ws = (char*)d_ws;
    const size_t MB = 1024 * 1024;
    u16*   wt_o   = (u16*)(ws);
    float* biasf  = (float*)(ws + 2 * MB);
    u16*   wt_qkv = (u16*)(ws + 3 * MB);  // 3072 x 1024
    u16*   key    = (u16*)(ws + 9 * MB);
    u16*   qry    = (u16*)(ws + 25 * MB);

    transpose_w4_kernel<<<dim3(16, 16, 4), dim3(64, 4), 0, stream>>>(
        Wq, Wk, Wv, Wo,
        wt_qkv, wt_qkv + 1024 * 1024, wt_qkv + 2 * 1024 * 1024, wt_o, x);
    convert_bias_kernel<<<dim3(4, 4), 256, 0, stream>>>(
        bq, bk, bv, bo, biasf, x);

    if (ws_size >= (size_t)121 * MB) {
        // Path A: one fused QKV GEMM (1536 blocks; 36KB LDS -> 4 blocks/CU)
        u16*   vt  = (u16*)(ws + 41 * MB);
        float* tmp = (float*)(ws + 57 * MB);
        u16*   orm = (u16*)(ws + 57 * MB);
        gemm_qkv_kernel<<<dim3(24, 64), 256, 0, stream>>>(
            x, wt_qkv, biasf, tmp, vt);
        quantum2_kernel<<<4096, 256, 0, stream>>>(tmp, key, qry);
        attn_kernel<<<dim3(16, 64), 256, 0, stream>>>(qry, key, vt, orm);
        gemm_f32out_kernel<<<dim3(8, 64), 256, 0, stream>>>(
            orm, 1, 0, wt_o, biasf + 3 * 1024, (float*)d_out, 1024);
    } else {
        // Path B: QK fused x2 + separate V (all reg-staged pipelines)
        float* tmp = (float*)(ws + 41 * MB);
        u16*   vt  = (u16*)(ws + 41 * MB);
        u16*   orm = (u16*)(ws + 57 * MB);
        for (int hh = 0; hh < 2; hh++) {
            gemm_f32out_kernel<<<dim3(16, 32), 256, 0, stream>>>(
                x, -1, hh * 4096, wt_qkv, biasf, tmp, 2048);
            quantum2_kernel<<<2048, 256, 0, stream>>>(
                tmp, key + (size_t)hh * 4096 * E_, qry + (size_t)hh * 4096 * E_);
        }
        gemm_v_fused_kernel<<<dim3(8, 64), 256, 0, stream>>>(
            x, wt_qkv + 2 * 1024 * 1024, biasf + 2 * 1024, vt);
        attn_kernel<<<dim3(16, 64), 256, 0, stream>>>(qry, key, vt, orm);
        gemm_f32out_kernel<<<dim3(8, 64), 256, 0, stream>>>(
            orm, 1, 0, wt_o, biasf + 3 * 1024, (float*)d_out, 1024);
    }
}